// Round 1
// baseline (5636.223 us; speedup 1.0000x reference)
//
#include <hip/hip_runtime.h>
#include <cstdint>

typedef _Float16 f16;
typedef _Float16 f16x8 __attribute__((ext_vector_type(8)));
typedef float    f32x4 __attribute__((ext_vector_type(4)));

#define DINL __device__ __forceinline__

static constexpr int HID = 1024;
static constexpr int NG  = 4096;   // 4*HID gate count
static constexpr int BB  = 256;    // batch
static constexpr int TT  = 100;    // seq len
static constexpr int KX  = 256;    // padded input-feature K (227 -> 256)
static constexpr size_t MSZ = (size_t)NG * HID;   // halves per packed [4096][1024] mat

// ---- workspace layout (bytes). total ~118.6 MiB ----
static constexpr size_t OFF_PACKW5 = 0;                                   // 5 packed mats: Whh1,Wih2,Whh2,Wih3,Whh3
static constexpr size_t OFF_W1D    = OFF_PACKW5 + 5*MSZ*2;                // Wih1@Wd packed [4096][1024] f16
static constexpr size_t OFF_WIH1   = OFF_W1D   + MSZ*2;                   // Wih1 packed [4096][256] f16 (K padded)
static constexpr size_t OFF_WD     = OFF_WIH1  + (size_t)NG*KX*2;         // Wd packed [256][1024] f16 (N padded)
static constexpr size_t OFF_XPAD   = OFF_WD    + (size_t)256*HID*2;       // x fp16 [100][256][256]
static constexpr size_t OFF_BIAS   = OFF_XPAD  + (size_t)TT*BB*KX*2;      // 4 x [4096] f32: b1_forced,b1_free,b2,b3
static constexpr size_t OFF_C      = OFF_BIAS  + (size_t)4*NG*4;          // c state [3][256][1024] f32 (in-place)
static constexpr size_t OFF_HBUF   = OFF_C     + (size_t)3*BB*HID*4;      // h ping-pong [2 parity][2 layers][256][1024] f16
static constexpr size_t OFF_H2Z    = OFF_HBUF  + (size_t)4*BB*HID*2;      // zero h2 for t=0
static constexpr size_t OFF_H2ALL  = OFF_H2Z   + (size_t)BB*HID*2;        // h2 history [100][256][1024] f16

// ---- async global->LDS, 16B per lane, lane-linear LDS dest ----
DINL void async16(void* lds, const void* g){
  auto lp = reinterpret_cast<__attribute__((address_space(3))) unsigned int*>(
      reinterpret_cast<uintptr_t>(lds));
  auto gp = reinterpret_cast<const __attribute__((address_space(1))) unsigned int*>(
      reinterpret_cast<uintptr_t>(g));
  __builtin_amdgcn_global_load_lds(gp, lp, 16, 0, 0);
}

DINL float sigf(float x){
  x = fminf(fmaxf(x, -30.f), 30.f);
  return __fdividef(1.f, 1.f + __expf(-x));
}
DINL float tanh_fast(float x){
  x = fminf(fmaxf(x, -15.f), 15.f);
  float t = __expf(2.f*x);
  return __fdividef(t - 1.f, t + 1.f);
}

// ---- 128x128 GEMM tile core: C[128m x 128n] += A[m][k] * Bp[n][k]^T over K ----
// A row-major stride sA (halves); Bp row-major stride K (halves). 4 waves, each 64x64.
// LDS layout per tile: [row][8 phys chunks of 16B], phys = kg ^ (row&7)  (XOR swizzle).
DINL void gemm_tile(f32x4 acc[4][4],
                    const f16* __restrict__ A, int m0, int sA,
                    const f16* __restrict__ Bp, int n0, int K,
                    char* ldsA, char* ldsB, int w, int lane)
{
  const int m_w = (w>>1)*64, n_w = (w&1)*64, c15 = lane&15;
  for (int k0 = 0; k0 < K; k0 += 64){
    __syncthreads();
    #pragma unroll
    for (int q = 0; q < 4; q++){
      int r0  = w*32 + q*8;
      int row = r0 + (lane>>3);
      int kg  = (lane&7) ^ (row&7);
      async16(ldsA + r0*128, A  + (size_t)(m0+row)*sA + k0 + kg*8);
      async16(ldsB + r0*128, Bp + (size_t)(n0+row)*K  + k0 + kg*8);
    }
    __syncthreads();
    #pragma unroll
    for (int kw = 0; kw < 2; kw++){
      f16x8 af[4], bf[4];
      #pragma unroll
      for (int ti = 0; ti < 4; ti++){
        int row  = m_w + ti*16 + c15;
        int phys = (kw*4 + (lane>>4)) ^ (row&7);
        af[ti] = *(const f16x8*)(ldsA + row*128 + phys*16);
      }
      #pragma unroll
      for (int tj = 0; tj < 4; tj++){
        int row  = n_w + tj*16 + c15;
        int phys = (kw*4 + (lane>>4)) ^ (row&7);
        bf[tj] = *(const f16x8*)(ldsB + row*128 + phys*16);
      }
      #pragma unroll
      for (int ti = 0; ti < 4; ti++)
        #pragma unroll
        for (int tj = 0; tj < 4; tj++)
          acc[ti][tj] = __builtin_amdgcn_mfma_f32_16x16x32_f16(af[ti], bf[tj], acc[ti][tj], 0, 0, 0);
    }
  }
}

// ================= prep kernels =================

// pack 5 [4096][1024] fp32 mats -> fp16, row permute r=g*1024+j -> n=j*4+g
__global__ void k_pack5(const float* W0, const float* W1, const float* W2,
                        const float* W3, const float* W4, char* ws)
{
  f16* dst = (f16*)(ws + OFF_PACKW5);
  const int mat = blockIdx.y;
  const float* src = mat==0?W0 : mat==1?W1 : mat==2?W2 : mat==3?W3 : W4;
  int tid = blockIdx.x*256 + threadIdx.x;       // < 524288
  int n = tid >> 7, kc = tid & 127;
  int r = ((n&3) << 10) + (n >> 2);
  const float* s = src + (size_t)r*HID + kc*8;
  f16x8 o;
  #pragma unroll
  for (int i = 0; i < 8; i++) o[i] = (f16)s[i];
  *(f16x8*)(dst + (size_t)mat*MSZ + (size_t)n*HID + kc*8) = o;
}

__global__ void k_packwih1(const float* __restrict__ Wih1, char* ws){
  f16* dst = (f16*)(ws + OFF_WIH1);
  int n = blockIdx.x, k = threadIdx.x;
  int r = ((n&3) << 10) + (n >> 2);
  dst[(size_t)n*KX + k] = (k < 227) ? (f16)Wih1[(size_t)r*227 + k] : (f16)0.f;
}

__global__ void k_packwd(const float* __restrict__ Wd, char* ws){
  f16* dst = (f16*)(ws + OFF_WD);
  int o = blockIdx.x;
  #pragma unroll
  for (int j = 0; j < 4; j++){
    int k = threadIdx.x + j*256;
    dst[(size_t)o*HID + k] = (o < 227) ? (f16)Wd[(size_t)o*HID + k] : (f16)0.f;
  }
}

__global__ void k_xpad(const float* __restrict__ seq, char* ws){
  f16* dst = (f16*)(ws + OFF_XPAD);
  int idx = blockIdx.x*256 + threadIdx.x;       // < 100*256*256
  int t = idx >> 16, rem = idx & 65535, b = rem >> 8, k = rem & 255;
  dst[idx] = (k < 227) ? (f16)seq[(size_t)b*22700 + (size_t)t*227 + k] : (f16)0.f;
}

__global__ void k_bias(const float* bih1, const float* bhh1, const float* bih2, const float* bhh2,
                       const float* bih3, const float* bhh3, const float* Wih1, const float* bd,
                       char* ws)
{
  int n = blockIdx.x*256 + threadIdx.x;
  if (n >= NG) return;
  int r = ((n&3) << 10) + (n >> 2);
  float* b = (float*)(ws + OFF_BIAS);
  float bf = bih1[r] + bhh1[r];
  float s = 0.f;
  for (int o = 0; o < 227; o++) s += Wih1[(size_t)r*227 + o] * bd[o];
  b[n]        = bf;            // layer1 bias, teacher-forced steps
  b[NG + n]   = bf + s;        // layer1 bias, free-running steps (+ Wih1@bd)
  b[2*NG + n] = bih2[r] + bhh2[r];
  b[3*NG + n] = bih3[r] + bhh3[r];
}

// W1d = Wih1 @ Wd : [4096][1024], packed fp16 with the gate-interleave permute
__global__ void k_w1d(const float* __restrict__ Wih1, const float* __restrict__ Wd, char* ws)
{
  __shared__ float lw[16][228];
  f16* W1D = (f16*)(ws + OFF_W1D);
  const int h0 = blockIdx.x*64, n0 = blockIdx.y*16;
  for (int idx = threadIdx.x; idx < 16*227; idx += 256){
    int nl = idx / 227, o = idx - nl*227;
    int n = n0 + nl, r = ((n&3) << 10) + (n >> 2);
    lw[nl][o] = Wih1[(size_t)r*227 + o];
  }
  __syncthreads();
  const int h = h0 + (threadIdx.x & 63), nq = threadIdx.x >> 6;
  float acc[4] = {0.f, 0.f, 0.f, 0.f};
  for (int o = 0; o < 227; o++){
    float wd = Wd[(size_t)o*HID + h];
    #pragma unroll
    for (int q = 0; q < 4; q++) acc[q] += lw[nq*4 + q][o] * wd;
  }
  #pragma unroll
  for (int q = 0; q < 4; q++) W1D[(size_t)(n0 + nq*4 + q)*HID + h] = (f16)acc[q];
}

// ================= recurrent step kernel =================
// grid (32 htiles, 3 layers, 2 mtiles), 256 threads. Computes gates (2 K-chunks of GEMM)
// + fused LSTM cell epilogue. All A inputs are state from step t-1.
__global__ __launch_bounds__(256, 2) void k_step(char* __restrict__ ws, int t, int use_gt)
{
  __shared__ __align__(16) char ldsA[16384];
  __shared__ __align__(16) char ldsB[16384];
  const int w = threadIdx.x >> 6, lane = threadIdx.x & 63;
  const int col0 = blockIdx.x*128, layer = blockIdx.y, m0 = blockIdx.z*128;

  const f16* packW = (const f16*)(ws + OFF_PACKW5);
  const f16* W1D   = (const f16*)(ws + OFF_W1D);
  const f16* WIH1  = (const f16*)(ws + OFF_WIH1);
  const f16* XP    = (const f16*)(ws + OFF_XPAD) + (size_t)t*BB*KX;
  const float* biasb = (const float*)(ws + OFF_BIAS);
  float* Cst = (float*)(ws + OFF_C);
  f16* HB  = (f16*)(ws + OFF_HBUF);
  f16* H2Z = (f16*)(ws + OFF_H2Z);
  f16* H2A = (f16*)(ws + OFF_H2ALL);

  const int pr = t & 1, pw = pr ^ 1;
  const f16* h0p = HB + (size_t)(pr*2 + 0)*BB*HID;
  const f16* h1p = HB + (size_t)(pr*2 + 1)*BB*HID;
  const f16* h2p = (t == 0) ? H2Z : (H2A + (size_t)(t-1)*BB*HID);

  const f16 *A0, *A1, *B0, *B1; int K1, sA1;
  const float* biasp; f16* hout; float* cptr;
  if (layer == 0){
    A0 = h0p; B0 = packW;                         // h0 @ Whh1^T
    if (use_gt){ A1 = XP;  B1 = WIH1; K1 = KX;  sA1 = KX;  biasp = biasb; }
    else       { A1 = h2p; B1 = W1D;  K1 = HID; sA1 = HID; biasp = biasb + NG; }
    hout = HB + (size_t)(pw*2 + 0)*BB*HID; cptr = Cst;
  } else if (layer == 1){
    A0 = h0p; B0 = packW + MSZ;  A1 = h1p; B1 = packW + 2*MSZ; K1 = HID; sA1 = HID;
    biasp = biasb + 2*NG; hout = HB + (size_t)(pw*2 + 1)*BB*HID; cptr = Cst + (size_t)BB*HID;
  } else {
    A0 = h1p; B0 = packW + 3*MSZ; A1 = h2p; B1 = packW + 4*MSZ; K1 = HID; sA1 = HID;
    biasp = biasb + 3*NG; hout = H2A + (size_t)t*BB*HID; cptr = Cst + (size_t)2*BB*HID;
  }

  f32x4 acc[4][4];
  f32x4 zero = {0.f, 0.f, 0.f, 0.f};
  #pragma unroll
  for (int i = 0; i < 4; i++)
    #pragma unroll
    for (int j = 0; j < 4; j++) acc[i][j] = zero;

  gemm_tile(acc, A0, m0, HID, B0, col0, HID, ldsA, ldsB, w, lane);
  gemm_tile(acc, A1, m0, sA1, B1, col0, K1,  ldsA, ldsB, w, lane);

  // ---- fused LSTM cell epilogue. Packed col n = unit*4 + gate; 4 gates sit in 4 adjacent lanes.
  const int m_w = (w>>1)*64, n_w = (w&1)*64, quad = lane>>4, gl = lane&3, c15 = lane&15, sbase = lane&60;
  const int mbase = m0 + m_w;
  #pragma unroll
  for (int tj = 0; tj < 4; tj++){
    const int ncol = col0 + n_w + tj*16 + c15;
    const int unit = ncol >> 2;
    const float bn = biasp[ncol];
    float cp[16];
    #pragma unroll
    for (int ti = 0; ti < 4; ti++)
      #pragma unroll
      for (int r = 0; r < 4; r++)
        cp[ti*4 + r] = cptr[(size_t)(mbase + ti*16 + quad*4 + r)*HID + unit];
    #pragma unroll
    for (int ti = 0; ti < 4; ti++){
      f32x4 v = acc[ti][tj];
      #pragma unroll
      for (int r = 0; r < 4; r++){
        float x  = v[r] + bn;
        float xi = __shfl(x, sbase);
        float xf = __shfl(x, sbase + 1);
        float xg = __shfl(x, sbase + 2);
        float xo = __shfl(x, sbase + 3);
        float iv = sigf(xi), fv = sigf(xf), gv = tanh_fast(xg), ov = sigf(xo);
        float cn = fmaf(fv, cp[ti*4 + r], iv*gv);
        float hn = ov * tanh_fast(cn);
        int m = mbase + ti*16 + quad*4 + r;
        if (gl == 0)      cptr[(size_t)m*HID + unit] = cn;
        else if (gl == 1) hout[(size_t)m*HID + unit] = (f16)hn;
      }
    }
  }
}

// ================= final output GEMM: out[b, t*227+o] = h2(t) @ Wd^T + bd =================
__global__ __launch_bounds__(256, 2) void k_final(const char* __restrict__ ws,
                                                  const float* __restrict__ bd,
                                                  float* __restrict__ dout)
{
  __shared__ __align__(16) char ldsA[16384];
  __shared__ __align__(16) char ldsB[16384];
  const int w = threadIdx.x >> 6, lane = threadIdx.x & 63;
  const int n0 = blockIdx.x*128, m0 = blockIdx.y*128;
  const f16* A  = (const f16*)(ws + OFF_H2ALL);
  const f16* Bp = (const f16*)(ws + OFF_WD);

  f32x4 acc[4][4];
  f32x4 zero = {0.f, 0.f, 0.f, 0.f};
  #pragma unroll
  for (int i = 0; i < 4; i++)
    #pragma unroll
    for (int j = 0; j < 4; j++) acc[i][j] = zero;

  gemm_tile(acc, A, m0, HID, Bp, n0, HID, ldsA, ldsB, w, lane);

  const int m_w = (w>>1)*64, n_w = (w&1)*64, quad = lane>>4, c15 = lane&15;
  #pragma unroll
  for (int tj = 0; tj < 4; tj++){
    int o = n0 + n_w + tj*16 + c15;
    bool valid = (o < 227);
    float bn = valid ? bd[o] : 0.f;
    #pragma unroll
    for (int ti = 0; ti < 4; ti++){
      f32x4 v = acc[ti][tj];
      #pragma unroll
      for (int r = 0; r < 4; r++){
        int m = m0 + m_w + ti*16 + quad*4 + r;
        if (valid){
          int tt = m >> 8, b = m & 255;
          dout[(size_t)b*22700 + (size_t)tt*227 + o] = v[r] + bn;
        }
      }
    }
  }
}

// ================= host =================
extern "C" void kernel_launch(void* const* d_in, const int* in_sizes, int n_in,
                              void* d_out, int out_size, void* d_ws, size_t ws_size,
                              hipStream_t stream)
{
  (void)in_sizes; (void)n_in; (void)out_size; (void)ws_size;
  const float* seq  = (const float*)d_in[0];
  const float* Wih1 = (const float*)d_in[1];
  const float* Whh1 = (const float*)d_in[2];
  const float* bih1 = (const float*)d_in[3];
  const float* bhh1 = (const float*)d_in[4];
  const float* Wih2 = (const float*)d_in[5];
  const float* Whh2 = (const float*)d_in[6];
  const float* bih2 = (const float*)d_in[7];
  const float* bhh2 = (const float*)d_in[8];
  const float* Wih3 = (const float*)d_in[9];
  const float* Whh3 = (const float*)d_in[10];
  const float* bih3 = (const float*)d_in[11];
  const float* bhh3 = (const float*)d_in[12];
  const float* Wd   = (const float*)d_in[13];
  const float* bd   = (const float*)d_in[14];
  char* ws = (char*)d_ws;

  // zero-init recurrent state (ws is poisoned before every launch)
  hipMemsetAsync(ws + OFF_C,    0, (size_t)3*BB*HID*4, stream);   // c state
  hipMemsetAsync(ws + OFF_HBUF, 0, (size_t)2*BB*HID*2, stream);   // h parity-0
  hipMemsetAsync(ws + OFF_H2Z,  0, (size_t)BB*HID*2,   stream);   // h2 at t=-1

  k_pack5   <<<dim3(2048, 5), dim3(256), 0, stream>>>(Whh1, Wih2, Whh2, Wih3, Whh3, ws);
  k_packwih1<<<dim3(4096),    dim3(256), 0, stream>>>(Wih1, ws);
  k_packwd  <<<dim3(256),     dim3(256), 0, stream>>>(Wd, ws);
  k_xpad    <<<dim3(25600),   dim3(256), 0, stream>>>(seq, ws);
  k_bias    <<<dim3(16),      dim3(256), 0, stream>>>(bih1, bhh1, bih2, bhh2, bih3, bhh3, Wih1, bd, ws);
  k_w1d     <<<dim3(16, 256), dim3(256), 0, stream>>>(Wih1, Wd, ws);

  for (int t = 0; t < TT; t++){
    int ug = ((t % 10) < 5) ? 1 : 0;   // 5 teacher-forced, 5 free-running, repeating
    k_step<<<dim3(32, 3, 2), dim3(256), 0, stream>>>(ws, t, ug);
  }

  k_final<<<dim3(2, 200), dim3(256), 0, stream>>>((const char*)ws, bd, (float*)d_out);
}

// Round 2
// 5085.431 us; speedup vs baseline: 1.1083x; 1.1083x over previous
//
#include <hip/hip_runtime.h>
#include <cstdint>

typedef _Float16 f16;
typedef _Float16 f16x8 __attribute__((ext_vector_type(8)));
typedef float    f32x4 __attribute__((ext_vector_type(4)));

#define DINL __device__ __forceinline__

static constexpr int HID = 1024;
static constexpr int NG  = 4096;   // 4*HID gate count
static constexpr int BB  = 256;    // batch
static constexpr int TT  = 100;    // seq len
static constexpr int KX  = 256;    // padded input-feature K (227 -> 256)
static constexpr size_t MSZ = (size_t)NG * HID;   // halves per packed [4096][1024] mat

// ---- workspace layout (bytes). total ~121 MiB ----
static constexpr size_t OFF_PACKW5 = 0;                                   // 5 packed mats: Whh1,Wih2,Whh2,Wih3,Whh3
static constexpr size_t OFF_W1D    = OFF_PACKW5 + 5*MSZ*2;                // Wih1@Wd packed [4096][1024] f16
static constexpr size_t OFF_WIH1   = OFF_W1D   + MSZ*2;                   // Wih1 packed [4096][256] f16 (K padded)
static constexpr size_t OFF_WD     = OFF_WIH1  + (size_t)NG*KX*2;         // Wd packed [256][1024] f16 (N padded)
static constexpr size_t OFF_XPAD   = OFF_WD    + (size_t)256*HID*2;       // x fp16 [100][256][256]
static constexpr size_t OFF_BIAS   = OFF_XPAD  + (size_t)TT*BB*KX*2;      // 4 x [4096] f32
static constexpr size_t OFF_C      = OFF_BIAS  + (size_t)4*NG*4;          // c state [3][256][1024] f32
static constexpr size_t OFF_HBUF   = OFF_C     + (size_t)3*BB*HID*4;      // h ping-pong [2][2][256][1024] f16
static constexpr size_t OFF_H2Z    = OFF_HBUF  + (size_t)4*BB*HID*2;      // zero h2 for t=0
static constexpr size_t OFF_H2ALL  = OFF_H2Z   + (size_t)BB*HID*2;        // h2 history [100][256][1024] f16
// WdT scratch ([1024][256] f16, 512 KB) lives at OFF_H2ALL: consumed by k_w1d
// before the first k_step ever writes H2A[0]. Stream-ordered, no conflict.

// ---- async global->LDS, 16B per lane, lane-linear LDS dest ----
DINL void async16(void* lds, const void* g){
  auto lp = reinterpret_cast<__attribute__((address_space(3))) unsigned int*>(
      reinterpret_cast<uintptr_t>(lds));
  auto gp = reinterpret_cast<const __attribute__((address_space(1))) unsigned int*>(
      reinterpret_cast<uintptr_t>(g));
  __builtin_amdgcn_global_load_lds(gp, lp, 16, 0, 0);
}

DINL float sigf(float x){
  x = fminf(fmaxf(x, -30.f), 30.f);
  return __fdividef(1.f, 1.f + __expf(-x));
}
DINL float tanh_fast(float x){
  x = fminf(fmaxf(x, -15.f), 15.f);
  float t = __expf(2.f*x);
  return __fdividef(t - 1.f, t + 1.f);
}

// ---- single-buffered 128x128 tile core (used by k_w1d / k_final) ----
DINL void gemm_tile(f32x4 acc[4][4],
                    const f16* __restrict__ A, int m0, int sA,
                    const f16* __restrict__ Bp, int n0, int K,
                    char* ldsA, char* ldsB, int w, int lane)
{
  const int m_w = (w>>1)*64, n_w = (w&1)*64, c15 = lane&15;
  for (int k0 = 0; k0 < K; k0 += 64){
    __syncthreads();
    #pragma unroll
    for (int q = 0; q < 4; q++){
      int r0  = w*32 + q*8;
      int row = r0 + (lane>>3);
      int kg  = (lane&7) ^ (row&7);
      async16(ldsA + r0*128, A  + (size_t)(m0+row)*sA + k0 + kg*8);
      async16(ldsB + r0*128, Bp + (size_t)(n0+row)*K  + k0 + kg*8);
    }
    __syncthreads();
    #pragma unroll
    for (int kw = 0; kw < 2; kw++){
      f16x8 af[4], bf[4];
      #pragma unroll
      for (int ti = 0; ti < 4; ti++){
        int row  = m_w + ti*16 + c15;
        int phys = (kw*4 + (lane>>4)) ^ (row&7);
        af[ti] = *(const f16x8*)(ldsA + row*128 + phys*16);
      }
      #pragma unroll
      for (int tj = 0; tj < 4; tj++){
        int row  = n_w + tj*16 + c15;
        int phys = (kw*4 + (lane>>4)) ^ (row&7);
        bf[tj] = *(const f16x8*)(ldsB + row*128 + phys*16);
      }
      #pragma unroll
      for (int ti = 0; ti < 4; ti++)
        #pragma unroll
        for (int tj = 0; tj < 4; tj++)
          acc[ti][tj] = __builtin_amdgcn_mfma_f32_16x16x32_f16(af[ti], bf[tj], acc[ti][tj], 0, 0, 0);
    }
  }
}

// ================= prep kernels =================

__global__ void k_pack5(const float* W0, const float* W1, const float* W2,
                        const float* W3, const float* W4, char* ws)
{
  f16* dst = (f16*)(ws + OFF_PACKW5);
  const int mat = blockIdx.y;
  const float* src = mat==0?W0 : mat==1?W1 : mat==2?W2 : mat==3?W3 : W4;
  int tid = blockIdx.x*256 + threadIdx.x;       // < 524288
  int n = tid >> 7, kc = tid & 127;
  int r = ((n&3) << 10) + (n >> 2);
  const float* s = src + (size_t)r*HID + kc*8;
  f16x8 o;
  #pragma unroll
  for (int i = 0; i < 8; i++) o[i] = (f16)s[i];
  *(f16x8*)(dst + (size_t)mat*MSZ + (size_t)n*HID + kc*8) = o;
}

__global__ void k_packwih1(const float* __restrict__ Wih1, char* ws){
  f16* dst = (f16*)(ws + OFF_WIH1);
  int n = blockIdx.x, k = threadIdx.x;
  int r = ((n&3) << 10) + (n >> 2);
  dst[(size_t)n*KX + k] = (k < 227) ? (f16)Wih1[(size_t)r*227 + k] : (f16)0.f;
}

__global__ void k_packwd(const float* __restrict__ Wd, char* ws){
  f16* dst = (f16*)(ws + OFF_WD);
  int o = blockIdx.x;
  #pragma unroll
  for (int j = 0; j < 4; j++){
    int k = threadIdx.x + j*256;
    dst[(size_t)o*HID + k] = (o < 227) ? (f16)Wd[(size_t)o*HID + k] : (f16)0.f;
  }
}

// WdT [1024][256] f16 into scratch at OFF_H2ALL
__global__ void k_packwdt(const float* __restrict__ Wd, char* ws){
  f16* dst = (f16*)(ws + OFF_H2ALL);
  int h = blockIdx.x, o = threadIdx.x;
  dst[(size_t)h*KX + o] = (o < 227) ? (f16)Wd[(size_t)o*HID + h] : (f16)0.f;
}

__global__ void k_xpad(const float* __restrict__ seq, char* ws){
  f16* dst = (f16*)(ws + OFF_XPAD);
  int idx = blockIdx.x*256 + threadIdx.x;       // < 100*256*256
  int t = idx >> 16, rem = idx & 65535, b = rem >> 8, k = rem & 255;
  dst[idx] = (k < 227) ? (f16)seq[(size_t)b*22700 + (size_t)t*227 + k] : (f16)0.f;
}

__global__ void k_bias(const float* bih1, const float* bhh1, const float* bih2, const float* bhh2,
                       const float* bih3, const float* bhh3, const float* Wih1, const float* bd,
                       char* ws)
{
  int n = blockIdx.x*256 + threadIdx.x;
  if (n >= NG) return;
  int r = ((n&3) << 10) + (n >> 2);
  float* b = (float*)(ws + OFF_BIAS);
  float bf = bih1[r] + bhh1[r];
  float s = 0.f;
  for (int o = 0; o < 227; o++) s += Wih1[(size_t)r*227 + o] * bd[o];
  b[n]        = bf;
  b[NG + n]   = bf + s;
  b[2*NG + n] = bih2[r] + bhh2[r];
  b[3*NG + n] = bih3[r] + bhh3[r];
}

// W1d = Wih1 @ Wd via MFMA: A=WIH1 packed [4096][256], B=WdT [1024][256], K=256
__global__ __launch_bounds__(256, 2) void k_w1d(char* ws)
{
  __shared__ __align__(16) char ldsA[16384];
  __shared__ __align__(16) char ldsB[16384];
  const int w = threadIdx.x >> 6, lane = threadIdx.x & 63;
  const int n0 = blockIdx.x*128, m0 = blockIdx.y*128;
  const f16* A  = (const f16*)(ws + OFF_WIH1);
  const f16* Bp = (const f16*)(ws + OFF_H2ALL);   // WdT scratch
  f16* W1D = (f16*)(ws + OFF_W1D);

  f32x4 acc[4][4];
  f32x4 zero = {0.f, 0.f, 0.f, 0.f};
  #pragma unroll
  for (int i = 0; i < 4; i++)
    #pragma unroll
    for (int j = 0; j < 4; j++) acc[i][j] = zero;

  gemm_tile(acc, A, m0, KX, Bp, n0, KX, ldsA, ldsB, w, lane);

  const int m_w = (w>>1)*64, n_w = (w&1)*64, quad = lane>>4, c15 = lane&15;
  #pragma unroll
  for (int tj = 0; tj < 4; tj++){
    int col = n0 + n_w + tj*16 + c15;
    #pragma unroll
    for (int ti = 0; ti < 4; ti++){
      f32x4 v = acc[ti][tj];
      #pragma unroll
      for (int r = 0; r < 4; r++){
        int m = m0 + m_w + ti*16 + quad*4 + r;
        W1D[(size_t)m*HID + col] = (f16)v[r];
      }
    }
  }
}

// ================= recurrent step kernel (pipelined, double-buffered) =================
// grid (64 ntiles, 3 layers), 256 threads. Tile: 256m x 64n, BK=64, LDS dbuf 80 KB.
// Wave w owns rows [w*64, w*64+64), all 64 cols. Weights read exactly once per step.
__global__ __launch_bounds__(256, 1) void k_step(char* __restrict__ ws, int t, int use_gt)
{
  __shared__ __align__(16) char lds[81920];   // [buf][A 32K | B 8K]
  const int w = threadIdx.x >> 6, lane = threadIdx.x & 63;
  const int col0 = blockIdx.x*64, layer = blockIdx.y;

  const f16* packW = (const f16*)(ws + OFF_PACKW5);
  const f16* W1D   = (const f16*)(ws + OFF_W1D);
  const f16* WIH1  = (const f16*)(ws + OFF_WIH1);
  const f16* XP    = (const f16*)(ws + OFF_XPAD) + (size_t)t*BB*KX;
  const float* biasb = (const float*)(ws + OFF_BIAS);
  float* Cst = (float*)(ws + OFF_C);
  f16* HB  = (f16*)(ws + OFF_HBUF);
  f16* H2Z = (f16*)(ws + OFF_H2Z);
  f16* H2A = (f16*)(ws + OFF_H2ALL);

  const int pr = t & 1, pw = pr ^ 1;
  const f16* h0p = HB + (size_t)(pr*2 + 0)*BB*HID;
  const f16* h1p = HB + (size_t)(pr*2 + 1)*BB*HID;
  const f16* h2p = (t == 0) ? H2Z : (H2A + (size_t)(t-1)*BB*HID);

  const f16 *A0, *A1, *B0, *B1; int K1, sA1;
  const float* biasp; f16* hout; float* cptr;
  if (layer == 0){
    A0 = h0p; B0 = packW;
    if (use_gt){ A1 = XP;  B1 = WIH1; K1 = KX;  sA1 = KX;  biasp = biasb; }
    else       { A1 = h2p; B1 = W1D;  K1 = HID; sA1 = HID; biasp = biasb + NG; }
    hout = HB + (size_t)(pw*2 + 0)*BB*HID; cptr = Cst;
  } else if (layer == 1){
    A0 = h0p; B0 = packW + MSZ;  A1 = h1p; B1 = packW + 2*MSZ; K1 = HID; sA1 = HID;
    biasp = biasb + 2*NG; hout = HB + (size_t)(pw*2 + 1)*BB*HID; cptr = Cst + (size_t)BB*HID;
  } else {
    A0 = h1p; B0 = packW + 3*MSZ; A1 = h2p; B1 = packW + 4*MSZ; K1 = HID; sA1 = HID;
    biasp = biasb + 3*NG; hout = H2A + (size_t)t*BB*HID; cptr = Cst + (size_t)2*BB*HID;
  }
  const int ncmax = 16 + (K1 >> 6);

  const int rsub = lane >> 3, kg = lane & 7;

  auto issue = [&](int c, int buf){
    const f16* A; const f16* B; int kk, sA, sB;
    if (c < 16){ A = A0; B = B0; kk = c*64;      sA = HID; sB = HID; }
    else       { A = A1; B = B1; kk = (c-16)*64; sA = sA1; sB = K1;  }
    char* lA = lds + buf*40960;
    char* lB = lA + 32768;
    #pragma unroll
    for (int q = 0; q < 8; q++){
      int r0  = q*32 + w*8;
      int row = r0 + rsub;
      int kx  = (kg ^ (row & 7)) * 8;
      async16(lA + r0*128, A + (size_t)row*sA + kk + kx);
    }
    #pragma unroll
    for (int q = 0; q < 2; q++){
      int r0  = q*32 + w*8;
      int row = r0 + rsub;
      int kx  = (kg ^ (row & 7)) * 8;
      async16(lB + r0*128, B + (size_t)(col0 + row)*sB + kk + kx);
    }
  };

  f32x4 acc[4][4];
  f32x4 zero = {0.f, 0.f, 0.f, 0.f};
  #pragma unroll
  for (int i = 0; i < 4; i++)
    #pragma unroll
    for (int j = 0; j < 4; j++) acc[i][j] = zero;

  const int m_w = w*64, c15 = lane&15, quad = lane>>4;

  issue(0, 0);
  __syncthreads();                     // cold-start drain of chunk 0
  for (int c = 0; c < ncmax; c++){
    if (c + 1 < ncmax) issue(c + 1, (c + 1) & 1);   // prefetch next chunk
    char* lA = lds + (c & 1)*40960;
    char* lB = lA + 32768;
    #pragma unroll
    for (int kw = 0; kw < 2; kw++){
      f16x8 af[4], bf[4];
      #pragma unroll
      for (int ti = 0; ti < 4; ti++){
        int row  = m_w + ti*16 + c15;
        int phys = (kw*4 + quad) ^ (row&7);
        af[ti] = *(const f16x8*)(lA + row*128 + phys*16);
      }
      #pragma unroll
      for (int tj = 0; tj < 4; tj++){
        int row  = tj*16 + c15;
        int phys = (kw*4 + quad) ^ (row&7);
        bf[tj] = *(const f16x8*)(lB + row*128 + phys*16);
      }
      #pragma unroll
      for (int ti = 0; ti < 4; ti++)
        #pragma unroll
        for (int tj = 0; tj < 4; tj++)
          acc[ti][tj] = __builtin_amdgcn_mfma_f32_16x16x32_f16(af[ti], bf[tj], acc[ti][tj], 0, 0, 0);
    }
    __syncthreads();   // drains prefetch (overlapped with this chunk's compute)
  }

  // ---- fused LSTM cell epilogue ----
  const int gl = lane&3, sbase = lane&60;
  #pragma unroll
  for (int tj = 0; tj < 4; tj++){
    const int ncol = col0 + tj*16 + c15;
    const int unit = ncol >> 2;
    const float bn = biasp[ncol];
    float cp[16];
    #pragma unroll
    for (int ti = 0; ti < 4; ti++)
      #pragma unroll
      for (int r = 0; r < 4; r++)
        cp[ti*4 + r] = cptr[(size_t)(m_w + ti*16 + quad*4 + r)*HID + unit];
    #pragma unroll
    for (int ti = 0; ti < 4; ti++){
      f32x4 v = acc[ti][tj];
      #pragma unroll
      for (int r = 0; r < 4; r++){
        float x  = v[r] + bn;
        float xi = __shfl(x, sbase);
        float xf = __shfl(x, sbase + 1);
        float xg = __shfl(x, sbase + 2);
        float xo = __shfl(x, sbase + 3);
        float iv = sigf(xi), fv = sigf(xf), gv = tanh_fast(xg), ov = sigf(xo);
        float cn = fmaf(fv, cp[ti*4 + r], iv*gv);
        float hn = ov * tanh_fast(cn);
        int m = m_w + ti*16 + quad*4 + r;
        if (gl == 0)      cptr[(size_t)m*HID + unit] = cn;
        else if (gl == 1) hout[(size_t)m*HID + unit] = (f16)hn;
      }
    }
  }
}

// ================= final output GEMM =================
__global__ __launch_bounds__(256, 2) void k_final(const char* __restrict__ ws,
                                                  const float* __restrict__ bd,
                                                  float* __restrict__ dout)
{
  __shared__ __align__(16) char ldsA[16384];
  __shared__ __align__(16) char ldsB[16384];
  const int w = threadIdx.x >> 6, lane = threadIdx.x & 63;
  const int n0 = blockIdx.x*128, m0 = blockIdx.y*128;
  const f16* A  = (const f16*)(ws + OFF_H2ALL);
  const f16* Bp = (const f16*)(ws + OFF_WD);

  f32x4 acc[4][4];
  f32x4 zero = {0.f, 0.f, 0.f, 0.f};
  #pragma unroll
  for (int i = 0; i < 4; i++)
    #pragma unroll
    for (int j = 0; j < 4; j++) acc[i][j] = zero;

  gemm_tile(acc, A, m0, HID, Bp, n0, HID, ldsA, ldsB, w, lane);

  const int m_w = (w>>1)*64, n_w = (w&1)*64, quad = lane>>4, c15 = lane&15;
  #pragma unroll
  for (int tj = 0; tj < 4; tj++){
    int o = n0 + n_w + tj*16 + c15;
    bool valid = (o < 227);
    float bn = valid ? bd[o] : 0.f;
    #pragma unroll
    for (int ti = 0; ti < 4; ti++){
      f32x4 v = acc[ti][tj];
      #pragma unroll
      for (int r = 0; r < 4; r++){
        int m = m0 + m_w + ti*16 + quad*4 + r;
        if (valid){
          int tt = m >> 8, b = m & 255;
          dout[(size_t)b*22700 + (size_t)tt*227 + o] = v[r] + bn;
        }
      }
    }
  }
}

// ================= host =================
extern "C" void kernel_launch(void* const* d_in, const int* in_sizes, int n_in,
                              void* d_out, int out_size, void* d_ws, size_t ws_size,
                              hipStream_t stream)
{
  (void)in_sizes; (void)n_in; (void)out_size; (void)ws_size;
  const float* seq  = (const float*)d_in[0];
  const float* Wih1 = (const float*)d_in[1];
  const float* Whh1 = (const float*)d_in[2];
  const float* bih1 = (const float*)d_in[3];
  const float* bhh1 = (const float*)d_in[4];
  const float* Wih2 = (const float*)d_in[5];
  const float* Whh2 = (const float*)d_in[6];
  const float* bih2 = (const float*)d_in[7];
  const float* bhh2 = (const float*)d_in[8];
  const float* Wih3 = (const float*)d_in[9];
  const float* Whh3 = (const float*)d_in[10];
  const float* bih3 = (const float*)d_in[11];
  const float* bhh3 = (const float*)d_in[12];
  const float* Wd   = (const float*)d_in[13];
  const float* bd   = (const float*)d_in[14];
  char* ws = (char*)d_ws;

  hipMemsetAsync(ws + OFF_C,    0, (size_t)3*BB*HID*4, stream);
  hipMemsetAsync(ws + OFF_HBUF, 0, (size_t)2*BB*HID*2, stream);
  hipMemsetAsync(ws + OFF_H2Z,  0, (size_t)BB*HID*2,   stream);

  k_pack5   <<<dim3(2048, 5), dim3(256), 0, stream>>>(Whh1, Wih2, Whh2, Wih3, Whh3, ws);
  k_packwih1<<<dim3(4096),    dim3(256), 0, stream>>>(Wih1, ws);
  k_packwd  <<<dim3(256),     dim3(256), 0, stream>>>(Wd, ws);
  k_packwdt <<<dim3(1024),    dim3(256), 0, stream>>>(Wd, ws);
  k_xpad    <<<dim3(25600),   dim3(256), 0, stream>>>(seq, ws);
  k_bias    <<<dim3(16),      dim3(256), 0, stream>>>(bih1, bhh1, bih2, bhh2, bih3, bhh3, Wih1, bd, ws);
  k_w1d     <<<dim3(8, 32),   dim3(256), 0, stream>>>(ws);

  for (int t = 0; t < TT; t++){
    int ug = ((t % 10) < 5) ? 1 : 0;
    k_step<<<dim3(64, 3), dim3(256), 0, stream>>>(ws, t, ug);
  }

  k_final<<<dim3(2, 200), dim3(256), 0, stream>>>((const char*)ws, bd, (float*)d_out);
}

// Round 3
// 4123.109 us; speedup vs baseline: 1.3670x; 1.2334x over previous
//
#include <hip/hip_runtime.h>
#include <cstdint>

typedef _Float16 f16;
typedef _Float16 f16x8 __attribute__((ext_vector_type(8)));
typedef float    f32x4 __attribute__((ext_vector_type(4)));

#define DINL __device__ __forceinline__

static constexpr int HID = 1024;
static constexpr int NG  = 4096;   // 4*HID gate count
static constexpr int BB  = 256;    // batch
static constexpr int TT  = 100;    // seq len
static constexpr int KX  = 256;    // padded input-feature K (227 -> 256)
static constexpr size_t MSZ = (size_t)NG * HID;   // halves per packed [4096][1024] mat

// ---- workspace layout (bytes). total ~119 MiB ----
static constexpr size_t OFF_PACKW5 = 0;
static constexpr size_t OFF_W1D    = OFF_PACKW5 + 5*MSZ*2;
static constexpr size_t OFF_WIH1   = OFF_W1D   + MSZ*2;
static constexpr size_t OFF_WD     = OFF_WIH1  + (size_t)NG*KX*2;
static constexpr size_t OFF_XPAD   = OFF_WD    + (size_t)256*HID*2;
static constexpr size_t OFF_BIAS   = OFF_XPAD  + (size_t)TT*BB*KX*2;
static constexpr size_t OFF_C      = OFF_BIAS  + (size_t)4*NG*4;
static constexpr size_t OFF_HBUF   = OFF_C     + (size_t)3*BB*HID*4;
static constexpr size_t OFF_H2Z    = OFF_HBUF  + (size_t)4*BB*HID*2;
static constexpr size_t OFF_H2ALL  = OFF_H2Z   + (size_t)BB*HID*2;
// WdT scratch ([1024][256] f16) lives at OFF_H2ALL until k_w1d consumes it.

DINL void async16(void* lds, const void* g){
  auto lp = reinterpret_cast<__attribute__((address_space(3))) unsigned int*>(
      reinterpret_cast<uintptr_t>(lds));
  auto gp = reinterpret_cast<const __attribute__((address_space(1))) unsigned int*>(
      reinterpret_cast<uintptr_t>(g));
  __builtin_amdgcn_global_load_lds(gp, lp, 16, 0, 0);
}

DINL float sigf(float x){
  x = fminf(fmaxf(x, -30.f), 30.f);
  return __fdividef(1.f, 1.f + __expf(-x));
}
DINL float tanh_fast(float x){
  x = fminf(fmaxf(x, -15.f), 15.f);
  float t = __expf(2.f*x);
  return __fdividef(t - 1.f, t + 1.f);
}

// ---- single-buffered 128x128 tile core (k_w1d / k_final only) ----
DINL void gemm_tile(f32x4 acc[4][4],
                    const f16* __restrict__ A, int m0, int sA,
                    const f16* __restrict__ Bp, int n0, int K,
                    char* ldsA, char* ldsB, int w, int lane)
{
  const int m_w = (w>>1)*64, n_w = (w&1)*64, c15 = lane&15;
  for (int k0 = 0; k0 < K; k0 += 64){
    __syncthreads();
    #pragma unroll
    for (int q = 0; q < 4; q++){
      int r0  = w*32 + q*8;
      int row = r0 + (lane>>3);
      int kg  = (lane&7) ^ (row&7);
      async16(ldsA + r0*128, A  + (size_t)(m0+row)*sA + k0 + kg*8);
      async16(ldsB + r0*128, Bp + (size_t)(n0+row)*K  + k0 + kg*8);
    }
    __syncthreads();
    #pragma unroll
    for (int kw = 0; kw < 2; kw++){
      f16x8 af[4], bf[4];
      #pragma unroll
      for (int ti = 0; ti < 4; ti++){
        int row  = m_w + ti*16 + c15;
        int phys = (kw*4 + (lane>>4)) ^ (row&7);
        af[ti] = *(const f16x8*)(ldsA + row*128 + phys*16);
      }
      #pragma unroll
      for (int tj = 0; tj < 4; tj++){
        int row  = n_w + tj*16 + c15;
        int phys = (kw*4 + (lane>>4)) ^ (row&7);
        bf[tj] = *(const f16x8*)(ldsB + row*128 + phys*16);
      }
      #pragma unroll
      for (int ti = 0; ti < 4; ti++)
        #pragma unroll
        for (int tj = 0; tj < 4; tj++)
          acc[ti][tj] = __builtin_amdgcn_mfma_f32_16x16x32_f16(af[ti], bf[tj], acc[ti][tj], 0, 0, 0);
    }
  }
}

// ================= prep kernels =================

__global__ void k_pack5(const float* W0, const float* W1, const float* W2,
                        const float* W3, const float* W4, char* ws)
{
  f16* dst = (f16*)(ws + OFF_PACKW5);
  const int mat = blockIdx.y;
  const float* src = mat==0?W0 : mat==1?W1 : mat==2?W2 : mat==3?W3 : W4;
  int tid = blockIdx.x*256 + threadIdx.x;
  int n = tid >> 7, kc = tid & 127;
  int r = ((n&3) << 10) + (n >> 2);
  const float* s = src + (size_t)r*HID + kc*8;
  f16x8 o;
  #pragma unroll
  for (int i = 0; i < 8; i++) o[i] = (f16)s[i];
  *(f16x8*)(dst + (size_t)mat*MSZ + (size_t)n*HID + kc*8) = o;
}

__global__ void k_packwih1(const float* __restrict__ Wih1, char* ws){
  f16* dst = (f16*)(ws + OFF_WIH1);
  int n = blockIdx.x, k = threadIdx.x;
  int r = ((n&3) << 10) + (n >> 2);
  dst[(size_t)n*KX + k] = (k < 227) ? (f16)Wih1[(size_t)r*227 + k] : (f16)0.f;
}

__global__ void k_packwd(const float* __restrict__ Wd, char* ws){
  f16* dst = (f16*)(ws + OFF_WD);
  int o = blockIdx.x;
  #pragma unroll
  for (int j = 0; j < 4; j++){
    int k = threadIdx.x + j*256;
    dst[(size_t)o*HID + k] = (o < 227) ? (f16)Wd[(size_t)o*HID + k] : (f16)0.f;
  }
}

__global__ void k_packwdt(const float* __restrict__ Wd, char* ws){
  f16* dst = (f16*)(ws + OFF_H2ALL);
  int h = blockIdx.x, o = threadIdx.x;
  dst[(size_t)h*KX + o] = (o < 227) ? (f16)Wd[(size_t)o*HID + h] : (f16)0.f;
}

__global__ void k_xpad(const float* __restrict__ seq, char* ws){
  f16* dst = (f16*)(ws + OFF_XPAD);
  int idx = blockIdx.x*256 + threadIdx.x;
  int t = idx >> 16, rem = idx & 65535, b = rem >> 8, k = rem & 255;
  dst[idx] = (k < 227) ? (f16)seq[(size_t)b*22700 + (size_t)t*227 + k] : (f16)0.f;
}

__global__ void k_bias(const float* bih1, const float* bhh1, const float* bih2, const float* bhh2,
                       const float* bih3, const float* bhh3, const float* Wih1, const float* bd,
                       char* ws)
{
  int n = blockIdx.x*256 + threadIdx.x;
  if (n >= NG) return;
  int r = ((n&3) << 10) + (n >> 2);
  float* b = (float*)(ws + OFF_BIAS);
  float bf = bih1[r] + bhh1[r];
  float s = 0.f;
  for (int o = 0; o < 227; o++) s += Wih1[(size_t)r*227 + o] * bd[o];
  b[n]        = bf;
  b[NG + n]   = bf + s;
  b[2*NG + n] = bih2[r] + bhh2[r];
  b[3*NG + n] = bih3[r] + bhh3[r];
}

__global__ __launch_bounds__(256, 2) void k_w1d(char* ws)
{
  __shared__ __align__(16) char ldsA[16384];
  __shared__ __align__(16) char ldsB[16384];
  const int w = threadIdx.x >> 6, lane = threadIdx.x & 63;
  const int n0 = blockIdx.x*128, m0 = blockIdx.y*128;
  const f16* A  = (const f16*)(ws + OFF_WIH1);
  const f16* Bp = (const f16*)(ws + OFF_H2ALL);
  f16* W1D = (f16*)(ws + OFF_W1D);

  f32x4 acc[4][4];
  f32x4 zero = {0.f, 0.f, 0.f, 0.f};
  #pragma unroll
  for (int i = 0; i < 4; i++)
    #pragma unroll
    for (int j = 0; j < 4; j++) acc[i][j] = zero;

  gemm_tile(acc, A, m0, KX, Bp, n0, KX, ldsA, ldsB, w, lane);

  const int m_w = (w>>1)*64, n_w = (w&1)*64, quad = lane>>4, c15 = lane&15;
  #pragma unroll
  for (int tj = 0; tj < 4; tj++){
    int col = n0 + n_w + tj*16 + c15;
    #pragma unroll
    for (int ti = 0; ti < 4; ti++){
      f32x4 v = acc[ti][tj];
      #pragma unroll
      for (int r = 0; r < 4; r++){
        int m = m0 + m_w + ti*16 + quad*4 + r;
        W1D[(size_t)m*HID + col] = (f16)v[r];
      }
    }
  }
}

// ================= recurrent step kernel: depth-4 vmcnt pipeline =================
// grid (64 ntiles, 3 layers), 256 threads, Tm=256 x Tn=64, BK=64.
// 4 LDS buffers x 40KB = 160KB (full CU). 3 chunks (120KB) kept in flight via
// s_waitcnt vmcnt(20) + raw s_barrier (NOT __syncthreads -> no vmcnt(0) drain).
__global__ __launch_bounds__(256, 1) void k_step(char* __restrict__ ws, int t, int use_gt)
{
  __shared__ __align__(16) char lds[163840];
  const int w = threadIdx.x >> 6, lane = threadIdx.x & 63;
  const int col0 = blockIdx.x*64, layer = blockIdx.y;

  const f16* packW = (const f16*)(ws + OFF_PACKW5);
  const f16* W1D   = (const f16*)(ws + OFF_W1D);
  const f16* WIH1  = (const f16*)(ws + OFF_WIH1);
  const f16* XP    = (const f16*)(ws + OFF_XPAD) + (size_t)t*BB*KX;
  const float* biasb = (const float*)(ws + OFF_BIAS);
  float* Cst = (float*)(ws + OFF_C);
  f16* HB  = (f16*)(ws + OFF_HBUF);
  f16* H2Z = (f16*)(ws + OFF_H2Z);
  f16* H2A = (f16*)(ws + OFF_H2ALL);

  const int pr = t & 1, pw = pr ^ 1;
  const f16* h0p = HB + (size_t)(pr*2 + 0)*BB*HID;
  const f16* h1p = HB + (size_t)(pr*2 + 1)*BB*HID;
  const f16* h2p = (t == 0) ? H2Z : (H2A + (size_t)(t-1)*BB*HID);

  const f16 *A0, *A1, *B0, *B1; int K1, sA1;
  const float* biasp; f16* hout; float* cptr;
  if (layer == 0){
    A0 = h0p; B0 = packW;
    if (use_gt){ A1 = XP;  B1 = WIH1; K1 = KX;  sA1 = KX;  biasp = biasb; }
    else       { A1 = h2p; B1 = W1D;  K1 = HID; sA1 = HID; biasp = biasb + NG; }
    hout = HB + (size_t)(pw*2 + 0)*BB*HID; cptr = Cst;
  } else if (layer == 1){
    A0 = h0p; B0 = packW + MSZ;  A1 = h1p; B1 = packW + 2*MSZ; K1 = HID; sA1 = HID;
    biasp = biasb + 2*NG; hout = HB + (size_t)(pw*2 + 1)*BB*HID; cptr = Cst + (size_t)BB*HID;
  } else {
    A0 = h1p; B0 = packW + 3*MSZ; A1 = h2p; B1 = packW + 4*MSZ; K1 = HID; sA1 = HID;
    biasp = biasb + 3*NG; hout = H2A + (size_t)t*BB*HID; cptr = Cst + (size_t)2*BB*HID;
  }
  const int ncmax = 16 + (K1 >> 6);

  // per-lane DMA base addresses: only +c*128B varies per chunk
  const int rsub = lane >> 3, kg = lane & 7;
  const int kxe  = (kg ^ rsub) * 8;              // XOR-swizzled k-chunk (elements)
  const int laneA = w*8 + rsub;
  const f16* baseA0 = A0 + (size_t)laneA*HID + kxe;
  const f16* baseB0 = B0 + (size_t)(col0 + laneA)*HID + kxe;
  const f16* baseA1 = A1 + (size_t)laneA*sA1 + kxe;
  const f16* baseB1 = B1 + (size_t)(col0 + laneA)*K1 + kxe;
  const size_t qA1 = 32*(size_t)sA1, qB1 = 32*(size_t)K1, q0 = 32*(size_t)HID;
  const int ldwb = w*8*128;                      // wave's LDS row-block byte offset

  auto issue = [&](int c){
    char* lA = lds + (size_t)(c & 3)*40960;
    char* lB = lA + 32768;
    const f16 *bA, *bB; int kk; size_t qA, qB;
    if (c < 16){ bA = baseA0; bB = baseB0; kk = c*64;      qA = q0;  qB = q0;  }
    else       { bA = baseA1; bB = baseB1; kk = (c-16)*64; qA = qA1; qB = qB1; }
    #pragma unroll
    for (int q = 0; q < 8; q++)
      async16(lA + q*4096 + ldwb, bA + q*qA + kk);
    #pragma unroll
    for (int q = 0; q < 2; q++)
      async16(lB + q*4096 + ldwb, bB + q*qB + kk);
  };

  f32x4 acc[4][4];
  f32x4 zero = {0.f, 0.f, 0.f, 0.f};
  #pragma unroll
  for (int i = 0; i < 4; i++)
    #pragma unroll
    for (int j = 0; j < 4; j++) acc[i][j] = zero;

  const int m_w = w*64, c15 = lane&15, quad = lane>>4;

  issue(0); issue(1); issue(2);                  // 30 DMA instrs / 120KB in flight
  for (int c = 0; c < ncmax; c++){
    // wait until THIS wave's chunk-c DMAs (oldest 10) are done; barrier makes it collective
    if (c + 2 < ncmax)      asm volatile("s_waitcnt vmcnt(20)" ::: "memory");
    else if (c + 1 < ncmax) asm volatile("s_waitcnt vmcnt(10)" ::: "memory");
    else                    asm volatile("s_waitcnt vmcnt(0)"  ::: "memory");
    __builtin_amdgcn_s_barrier();
    if (c + 3 < ncmax) issue(c + 3);             // overwrites buffer consumed at c-1: safe
    char* lA = lds + (size_t)(c & 3)*40960;
    char* lB = lA + 32768;
    #pragma unroll
    for (int kw = 0; kw < 2; kw++){
      f16x8 af[4], bf[4];
      #pragma unroll
      for (int ti = 0; ti < 4; ti++){
        int row  = m_w + ti*16 + c15;
        int phys = (kw*4 + quad) ^ (row&7);
        af[ti] = *(const f16x8*)(lA + row*128 + phys*16);
      }
      #pragma unroll
      for (int tj = 0; tj < 4; tj++){
        int row  = tj*16 + c15;
        int phys = (kw*4 + quad) ^ (row&7);
        bf[tj] = *(const f16x8*)(lB + row*128 + phys*16);
      }
      #pragma unroll
      for (int ti = 0; ti < 4; ti++)
        #pragma unroll
        for (int tj = 0; tj < 4; tj++)
          acc[ti][tj] = __builtin_amdgcn_mfma_f32_16x16x32_f16(af[ti], bf[tj], acc[ti][tj], 0, 0, 0);
    }
  }

  // ---- fused LSTM cell epilogue (per-lane single activation, shuffle after) ----
  const int gl = lane&3, sbase = lane&60;
  #pragma unroll
  for (int tj = 0; tj < 4; tj++){
    const int ncol = col0 + tj*16 + c15;
    const int unit = ncol >> 2;
    const float bn = biasp[ncol];
    float cp[16];
    #pragma unroll
    for (int ti = 0; ti < 4; ti++)
      #pragma unroll
      for (int r = 0; r < 4; r++)
        cp[ti*4 + r] = cptr[(size_t)(m_w + ti*16 + quad*4 + r)*HID + unit];
    #pragma unroll
    for (int ti = 0; ti < 4; ti++){
      f32x4 v = acc[ti][tj];
      #pragma unroll
      for (int r = 0; r < 4; r++){
        float x   = v[r] + bn;
        float act = (gl == 2) ? tanh_fast(x) : sigf(x);   // lane's own gate only
        float iv = __shfl(act, sbase);
        float fv = __shfl(act, sbase + 1);
        float gv = __shfl(act, sbase + 2);
        float ov = __shfl(act, sbase + 3);
        float cn = fmaf(fv, cp[ti*4 + r], iv*gv);
        float hn = ov * tanh_fast(cn);
        int m = m_w + ti*16 + quad*4 + r;
        if (gl == 0)      cptr[(size_t)m*HID + unit] = cn;
        else if (gl == 1) hout[(size_t)m*HID + unit] = (f16)hn;
      }
    }
  }
}

// ================= final output GEMM =================
__global__ __launch_bounds__(256, 2) void k_final(const char* __restrict__ ws,
                                                  const float* __restrict__ bd,
                                                  float* __restrict__ dout)
{
  __shared__ __align__(16) char ldsA[16384];
  __shared__ __align__(16) char ldsB[16384];
  const int w = threadIdx.x >> 6, lane = threadIdx.x & 63;
  const int n0 = blockIdx.x*128, m0 = blockIdx.y*128;
  const f16* A  = (const f16*)(ws + OFF_H2ALL);
  const f16* Bp = (const f16*)(ws + OFF_WD);

  f32x4 acc[4][4];
  f32x4 zero = {0.f, 0.f, 0.f, 0.f};
  #pragma unroll
  for (int i = 0; i < 4; i++)
    #pragma unroll
    for (int j = 0; j < 4; j++) acc[i][j] = zero;

  gemm_tile(acc, A, m0, HID, Bp, n0, HID, ldsA, ldsB, w, lane);

  const int m_w = (w>>1)*64, n_w = (w&1)*64, quad = lane>>4, c15 = lane&15;
  #pragma unroll
  for (int tj = 0; tj < 4; tj++){
    int o = n0 + n_w + tj*16 + c15;
    bool valid = (o < 227);
    float bn = valid ? bd[o] : 0.f;
    #pragma unroll
    for (int ti = 0; ti < 4; ti++){
      f32x4 v = acc[ti][tj];
      #pragma unroll
      for (int r = 0; r < 4; r++){
        int m = m0 + m_w + ti*16 + quad*4 + r;
        if (valid){
          int tt = m >> 8, b = m & 255;
          dout[(size_t)b*22700 + (size_t)tt*227 + o] = v[r] + bn;
        }
      }
    }
  }
}

// ================= host =================
extern "C" void kernel_launch(void* const* d_in, const int* in_sizes, int n_in,
                              void* d_out, int out_size, void* d_ws, size_t ws_size,
                              hipStream_t stream)
{
  (void)in_sizes; (void)n_in; (void)out_size; (void)ws_size;
  const float* seq  = (const float*)d_in[0];
  const float* Wih1 = (const float*)d_in[1];
  const float* Whh1 = (const float*)d_in[2];
  const float* bih1 = (const float*)d_in[3];
  const float* bhh1 = (const float*)d_in[4];
  const float* Wih2 = (const float*)d_in[5];
  const float* Whh2 = (const float*)d_in[6];
  const float* bih2 = (const float*)d_in[7];
  const float* bhh2 = (const float*)d_in[8];
  const float* Wih3 = (const float*)d_in[9];
  const float* Whh3 = (const float*)d_in[10];
  const float* bih3 = (const float*)d_in[11];
  const float* bhh3 = (const float*)d_in[12];
  const float* Wd   = (const float*)d_in[13];
  const float* bd   = (const float*)d_in[14];
  char* ws = (char*)d_ws;

  hipMemsetAsync(ws + OFF_C,    0, (size_t)3*BB*HID*4, stream);
  hipMemsetAsync(ws + OFF_HBUF, 0, (size_t)2*BB*HID*2, stream);
  hipMemsetAsync(ws + OFF_H2Z,  0, (size_t)BB*HID*2,   stream);

  k_pack5   <<<dim3(2048, 5), dim3(256), 0, stream>>>(Whh1, Wih2, Whh2, Wih3, Whh3, ws);
  k_packwih1<<<dim3(4096),    dim3(256), 0, stream>>>(Wih1, ws);
  k_packwd  <<<dim3(256),     dim3(256), 0, stream>>>(Wd, ws);
  k_packwdt <<<dim3(1024),    dim3(256), 0, stream>>>(Wd, ws);
  k_xpad    <<<dim3(25600),   dim3(256), 0, stream>>>(seq, ws);
  k_bias    <<<dim3(16),      dim3(256), 0, stream>>>(bih1, bhh1, bih2, bhh2, bih3, bhh3, Wih1, bd, ws);
  k_w1d     <<<dim3(8, 32),   dim3(256), 0, stream>>>(ws);

  for (int t = 0; t < TT; t++){
    int ug = ((t % 10) < 5) ? 1 : 0;
    k_step<<<dim3(64, 3), dim3(256), 0, stream>>>(ws, t, ug);
  }

  k_final<<<dim3(2, 200), dim3(256), 0, stream>>>((const char*)ws, bd, (float*)d_out);
}

// Round 4
// 4097.719 us; speedup vs baseline: 1.3755x; 1.0062x over previous
//
#include <hip/hip_runtime.h>
#include <cstdint>

typedef _Float16 f16;
typedef _Float16 f16x8 __attribute__((ext_vector_type(8)));
typedef float    f32x4 __attribute__((ext_vector_type(4)));

#define DINL __device__ __forceinline__

static constexpr int HID = 1024;
static constexpr int NG  = 4096;   // 4*HID gate count
static constexpr int BB  = 256;    // batch
static constexpr int TT  = 100;    // seq len
static constexpr int KX  = 256;    // padded input-feature K (227 -> 256)
static constexpr size_t MSZ = (size_t)NG * HID;   // halves per packed [4096][1024] mat

// ---- workspace layout (bytes). total ~119 MiB ----
static constexpr size_t OFF_PACKW5 = 0;
static constexpr size_t OFF_W1D    = OFF_PACKW5 + 5*MSZ*2;
static constexpr size_t OFF_WIH1   = OFF_W1D   + MSZ*2;
static constexpr size_t OFF_WD     = OFF_WIH1  + (size_t)NG*KX*2;
static constexpr size_t OFF_XPAD   = OFF_WD    + (size_t)256*HID*2;
static constexpr size_t OFF_BIAS   = OFF_XPAD  + (size_t)TT*BB*KX*2;
static constexpr size_t OFF_C      = OFF_BIAS  + (size_t)4*NG*4;
static constexpr size_t OFF_HBUF   = OFF_C     + (size_t)3*BB*HID*4;
static constexpr size_t OFF_H2Z    = OFF_HBUF  + (size_t)4*BB*HID*2;
static constexpr size_t OFF_H2ALL  = OFF_H2Z   + (size_t)BB*HID*2;
// WdT scratch ([1024][256] f16) lives at OFF_H2ALL until k_w1d consumes it.

DINL void async16(void* lds, const void* g){
  auto lp = reinterpret_cast<__attribute__((address_space(3))) unsigned int*>(
      reinterpret_cast<uintptr_t>(lds));
  auto gp = reinterpret_cast<const __attribute__((address_space(1))) unsigned int*>(
      reinterpret_cast<uintptr_t>(g));
  __builtin_amdgcn_global_load_lds(gp, lp, 16, 0, 0);
}

// LDS read via inline asm: invisible to the compiler's LDS-DMA waitcnt pass
// (prevents it from inserting s_waitcnt vmcnt(0) before aliasing ds_reads).
DINL f16x8 ldsr128(unsigned a){
  f16x8 r;
  asm volatile("ds_read_b128 %0, %1" : "=v"(r) : "v"(a));
  return r;
}

DINL float sigf(float x){
  x = fminf(fmaxf(x, -30.f), 30.f);
  return __fdividef(1.f, 1.f + __expf(-x));
}
DINL float tanh_fast(float x){
  x = fminf(fmaxf(x, -15.f), 15.f);
  float t = __expf(2.f*x);
  return __fdividef(t - 1.f, t + 1.f);
}

// ---- single-buffered 128x128 tile core (k_w1d / k_final only) ----
DINL void gemm_tile(f32x4 acc[4][4],
                    const f16* __restrict__ A, int m0, int sA,
                    const f16* __restrict__ Bp, int n0, int K,
                    char* ldsA, char* ldsB, int w, int lane)
{
  const int m_w = (w>>1)*64, n_w = (w&1)*64, c15 = lane&15;
  for (int k0 = 0; k0 < K; k0 += 64){
    __syncthreads();
    #pragma unroll
    for (int q = 0; q < 4; q++){
      int r0  = w*32 + q*8;
      int row = r0 + (lane>>3);
      int kg  = (lane&7) ^ (row&7);
      async16(ldsA + r0*128, A  + (size_t)(m0+row)*sA + k0 + kg*8);
      async16(ldsB + r0*128, Bp + (size_t)(n0+row)*K  + k0 + kg*8);
    }
    __syncthreads();
    #pragma unroll
    for (int kw = 0; kw < 2; kw++){
      f16x8 af[4], bf[4];
      #pragma unroll
      for (int ti = 0; ti < 4; ti++){
        int row  = m_w + ti*16 + c15;
        int phys = (kw*4 + (lane>>4)) ^ (row&7);
        af[ti] = *(const f16x8*)(ldsA + row*128 + phys*16);
      }
      #pragma unroll
      for (int tj = 0; tj < 4; tj++){
        int row  = n_w + tj*16 + c15;
        int phys = (kw*4 + (lane>>4)) ^ (row&7);
        bf[tj] = *(const f16x8*)(ldsB + row*128 + phys*16);
      }
      #pragma unroll
      for (int ti = 0; ti < 4; ti++)
        #pragma unroll
        for (int tj = 0; tj < 4; tj++)
          acc[ti][tj] = __builtin_amdgcn_mfma_f32_16x16x32_f16(af[ti], bf[tj], acc[ti][tj], 0, 0, 0);
    }
  }
}

// ================= prep kernels =================

__global__ void k_pack5(const float* W0, const float* W1, const float* W2,
                        const float* W3, const float* W4, char* ws)
{
  f16* dst = (f16*)(ws + OFF_PACKW5);
  const int mat = blockIdx.y;
  const float* src = mat==0?W0 : mat==1?W1 : mat==2?W2 : mat==3?W3 : W4;
  int tid = blockIdx.x*256 + threadIdx.x;
  int n = tid >> 7, kc = tid & 127;
  int r = ((n&3) << 10) + (n >> 2);
  const float* s = src + (size_t)r*HID + kc*8;
  f16x8 o;
  #pragma unroll
  for (int i = 0; i < 8; i++) o[i] = (f16)s[i];
  *(f16x8*)(dst + (size_t)mat*MSZ + (size_t)n*HID + kc*8) = o;
}

__global__ void k_packwih1(const float* __restrict__ Wih1, char* ws){
  f16* dst = (f16*)(ws + OFF_WIH1);
  int n = blockIdx.x, k = threadIdx.x;
  int r = ((n&3) << 10) + (n >> 2);
  dst[(size_t)n*KX + k] = (k < 227) ? (f16)Wih1[(size_t)r*227 + k] : (f16)0.f;
}

__global__ void k_packwd(const float* __restrict__ Wd, char* ws){
  f16* dst = (f16*)(ws + OFF_WD);
  int o = blockIdx.x;
  #pragma unroll
  for (int j = 0; j < 4; j++){
    int k = threadIdx.x + j*256;
    dst[(size_t)o*HID + k] = (o < 227) ? (f16)Wd[(size_t)o*HID + k] : (f16)0.f;
  }
}

__global__ void k_packwdt(const float* __restrict__ Wd, char* ws){
  f16* dst = (f16*)(ws + OFF_H2ALL);
  int h = blockIdx.x, o = threadIdx.x;
  dst[(size_t)h*KX + o] = (o < 227) ? (f16)Wd[(size_t)o*HID + h] : (f16)0.f;
}

__global__ void k_xpad(const float* __restrict__ seq, char* ws){
  f16* dst = (f16*)(ws + OFF_XPAD);
  int idx = blockIdx.x*256 + threadIdx.x;
  int t = idx >> 16, rem = idx & 65535, b = rem >> 8, k = rem & 255;
  dst[idx] = (k < 227) ? (f16)seq[(size_t)b*22700 + (size_t)t*227 + k] : (f16)0.f;
}

__global__ void k_bias(const float* bih1, const float* bhh1, const float* bih2, const float* bhh2,
                       const float* bih3, const float* bhh3, const float* Wih1, const float* bd,
                       char* ws)
{
  int n = blockIdx.x*256 + threadIdx.x;
  if (n >= NG) return;
  int r = ((n&3) << 10) + (n >> 2);
  float* b = (float*)(ws + OFF_BIAS);
  float bf = bih1[r] + bhh1[r];
  float s = 0.f;
  for (int o = 0; o < 227; o++) s += Wih1[(size_t)r*227 + o] * bd[o];
  b[n]        = bf;
  b[NG + n]   = bf + s;
  b[2*NG + n] = bih2[r] + bhh2[r];
  b[3*NG + n] = bih3[r] + bhh3[r];
}

__global__ __launch_bounds__(256, 2) void k_w1d(char* ws)
{
  __shared__ __align__(16) char ldsA[16384];
  __shared__ __align__(16) char ldsB[16384];
  const int w = threadIdx.x >> 6, lane = threadIdx.x & 63;
  const int n0 = blockIdx.x*128, m0 = blockIdx.y*128;
  const f16* A  = (const f16*)(ws + OFF_WIH1);
  const f16* Bp = (const f16*)(ws + OFF_H2ALL);
  f16* W1D = (f16*)(ws + OFF_W1D);

  f32x4 acc[4][4];
  f32x4 zero = {0.f, 0.f, 0.f, 0.f};
  #pragma unroll
  for (int i = 0; i < 4; i++)
    #pragma unroll
    for (int j = 0; j < 4; j++) acc[i][j] = zero;

  gemm_tile(acc, A, m0, KX, Bp, n0, KX, ldsA, ldsB, w, lane);

  const int m_w = (w>>1)*64, n_w = (w&1)*64, quad = lane>>4, c15 = lane&15;
  #pragma unroll
  for (int tj = 0; tj < 4; tj++){
    int col = n0 + n_w + tj*16 + c15;
    #pragma unroll
    for (int ti = 0; ti < 4; ti++){
      f32x4 v = acc[ti][tj];
      #pragma unroll
      for (int r = 0; r < 4; r++){
        int m = m0 + m_w + ti*16 + quad*4 + r;
        W1D[(size_t)m*HID + col] = (f16)v[r];
      }
    }
  }
}

// ================= recurrent step kernel: depth-4 vmcnt pipeline, asm ds_reads =================
// grid (64 ntiles, 3 layers), 256 threads, Tm=256 x Tn=64, BK=64.
// 4 LDS buffers x 40KB = 160KB. 3 chunks in flight via s_waitcnt vmcnt(20) + raw
// s_barrier. Fragment reads are inline-asm ds_read_b128 with manual lgkmcnt fences,
// so the compiler's LDS-DMA alias tracking cannot insert vmcnt(0) drains.
__global__ __launch_bounds__(256, 1) void k_step(char* __restrict__ ws, int t, int use_gt)
{
  __shared__ __align__(16) char lds[163840];
  const int w = threadIdx.x >> 6, lane = threadIdx.x & 63;
  const int col0 = blockIdx.x*64, layer = blockIdx.y;

  const f16* packW = (const f16*)(ws + OFF_PACKW5);
  const f16* W1D   = (const f16*)(ws + OFF_W1D);
  const f16* WIH1  = (const f16*)(ws + OFF_WIH1);
  const f16* XP    = (const f16*)(ws + OFF_XPAD) + (size_t)t*BB*KX;
  const float* biasb = (const float*)(ws + OFF_BIAS);
  float* Cst = (float*)(ws + OFF_C);
  f16* HB  = (f16*)(ws + OFF_HBUF);
  f16* H2Z = (f16*)(ws + OFF_H2Z);
  f16* H2A = (f16*)(ws + OFF_H2ALL);

  const int pr = t & 1, pw = pr ^ 1;
  const f16* h0p = HB + (size_t)(pr*2 + 0)*BB*HID;
  const f16* h1p = HB + (size_t)(pr*2 + 1)*BB*HID;
  const f16* h2p = (t == 0) ? H2Z : (H2A + (size_t)(t-1)*BB*HID);

  const f16 *A0, *A1, *B0, *B1; int K1, sA1;
  const float* biasp; f16* hout; float* cptr;
  if (layer == 0){
    A0 = h0p; B0 = packW;
    if (use_gt){ A1 = XP;  B1 = WIH1; K1 = KX;  sA1 = KX;  biasp = biasb; }
    else       { A1 = h2p; B1 = W1D;  K1 = HID; sA1 = HID; biasp = biasb + NG; }
    hout = HB + (size_t)(pw*2 + 0)*BB*HID; cptr = Cst;
  } else if (layer == 1){
    A0 = h0p; B0 = packW + MSZ;  A1 = h1p; B1 = packW + 2*MSZ; K1 = HID; sA1 = HID;
    biasp = biasb + 2*NG; hout = HB + (size_t)(pw*2 + 1)*BB*HID; cptr = Cst + (size_t)BB*HID;
  } else {
    A0 = h1p; B0 = packW + 3*MSZ; A1 = h2p; B1 = packW + 4*MSZ; K1 = HID; sA1 = HID;
    biasp = biasb + 3*NG; hout = H2A + (size_t)t*BB*HID; cptr = Cst + (size_t)2*BB*HID;
  }
  const int ncmax = 16 + (K1 >> 6);

  // per-lane DMA base addresses: only +c*128B varies per chunk
  const int rsub = lane >> 3, kg = lane & 7;
  const int kxe  = (kg ^ rsub) * 8;              // XOR-swizzled k-chunk (elements)
  const int laneA = w*8 + rsub;
  const f16* baseA0 = A0 + (size_t)laneA*HID + kxe;
  const f16* baseB0 = B0 + (size_t)(col0 + laneA)*HID + kxe;
  const f16* baseA1 = A1 + (size_t)laneA*sA1 + kxe;
  const f16* baseB1 = B1 + (size_t)(col0 + laneA)*K1 + kxe;
  const size_t qA1 = 32*(size_t)sA1, qB1 = 32*(size_t)K1, q0 = 32*(size_t)HID;
  const int ldwb = w*8*128;                      // wave's LDS row-block byte offset

  auto issue = [&](int c){
    char* lA = lds + (size_t)(c & 3)*40960;
    char* lB = lA + 32768;
    const f16 *bA, *bB; int kk; size_t qA, qB;
    if (c < 16){ bA = baseA0; bB = baseB0; kk = c*64;      qA = q0;  qB = q0;  }
    else       { bA = baseA1; bB = baseB1; kk = (c-16)*64; qA = qA1; qB = qB1; }
    #pragma unroll
    for (int q = 0; q < 8; q++)
      async16(lA + q*4096 + ldwb, bA + q*qA + kk);
    #pragma unroll
    for (int q = 0; q < 2; q++)
      async16(lB + q*4096 + ldwb, bB + q*qB + kk);
  };

  f32x4 acc[4][4];
  f32x4 zero = {0.f, 0.f, 0.f, 0.f};
  #pragma unroll
  for (int i = 0; i < 4; i++)
    #pragma unroll
    for (int j = 0; j < 4; j++) acc[i][j] = zero;

  const int m_w = w*64, c15 = lane&15, quad = lane>>4;

  // (row & 7) == (c15 & 7) for every fragment row -> swizzle phase is per-lane const
  const unsigned ldsBase = (unsigned)(uintptr_t)lds;
  const unsigned p0 = (unsigned)(( quad      ^ (c15&7)) * 16);   // kw=0 phase
  const unsigned p1 = (unsigned)(((4 + quad) ^ (c15&7)) * 16);   // kw=1 phase
  unsigned rA[4], rB[4];
  #pragma unroll
  for (int ti = 0; ti < 4; ti++) rA[ti] = (unsigned)((m_w + ti*16 + c15) * 128);
  #pragma unroll
  for (int tj = 0; tj < 4; tj++) rB[tj] = (unsigned)((tj*16 + c15) * 128) + 32768u;

  issue(0); issue(1); issue(2);                  // 30 DMA instrs / 120KB in flight
  for (int c = 0; c < ncmax; c++){
    // wait until THIS wave's chunk-c DMAs (oldest 10) are done; barrier makes it collective
    if (c + 2 < ncmax)      asm volatile("s_waitcnt vmcnt(20)" ::: "memory");
    else if (c + 1 < ncmax) asm volatile("s_waitcnt vmcnt(10)" ::: "memory");
    else                    asm volatile("s_waitcnt vmcnt(0)"  ::: "memory");
    __builtin_amdgcn_s_barrier();
    if (c + 3 < ncmax) issue(c + 3);             // overwrites buffer consumed at c-1: safe
    const unsigned ab = ldsBase + (unsigned)((c & 3)*40960);

    f16x8 a0[4], b0[4], a1[4], b1[4];
    #pragma unroll
    for (int ti = 0; ti < 4; ti++) a0[ti] = ldsr128(ab + rA[ti] + p0);
    #pragma unroll
    for (int tj = 0; tj < 4; tj++) b0[tj] = ldsr128(ab + rB[tj] + p0);
    #pragma unroll
    for (int ti = 0; ti < 4; ti++) a1[ti] = ldsr128(ab + rA[ti] + p1);
    #pragma unroll
    for (int tj = 0; tj < 4; tj++) b1[tj] = ldsr128(ab + rB[tj] + p1);

    asm volatile("s_waitcnt lgkmcnt(8)"
      : "+v"(a0[0]), "+v"(a0[1]), "+v"(a0[2]), "+v"(a0[3]),
        "+v"(b0[0]), "+v"(b0[1]), "+v"(b0[2]), "+v"(b0[3]));
    #pragma unroll
    for (int ti = 0; ti < 4; ti++)
      #pragma unroll
      for (int tj = 0; tj < 4; tj++)
        acc[ti][tj] = __builtin_amdgcn_mfma_f32_16x16x32_f16(a0[ti], b0[tj], acc[ti][tj], 0, 0, 0);

    asm volatile("s_waitcnt lgkmcnt(0)"
      : "+v"(a1[0]), "+v"(a1[1]), "+v"(a1[2]), "+v"(a1[3]),
        "+v"(b1[0]), "+v"(b1[1]), "+v"(b1[2]), "+v"(b1[3]));
    #pragma unroll
    for (int ti = 0; ti < 4; ti++)
      #pragma unroll
      for (int tj = 0; tj < 4; tj++)
        acc[ti][tj] = __builtin_amdgcn_mfma_f32_16x16x32_f16(a1[ti], b1[tj], acc[ti][tj], 0, 0, 0);
  }

  // ---- fused LSTM cell epilogue (per-lane single activation, shuffle after) ----
  const int gl = lane&3, sbase = lane&60;
  #pragma unroll
  for (int tj = 0; tj < 4; tj++){
    const int ncol = col0 + tj*16 + c15;
    const int unit = ncol >> 2;
    const float bn = biasp[ncol];
    float cp[16];
    #pragma unroll
    for (int ti = 0; ti < 4; ti++)
      #pragma unroll
      for (int r = 0; r < 4; r++)
        cp[ti*4 + r] = cptr[(size_t)(m_w + ti*16 + quad*4 + r)*HID + unit];
    #pragma unroll
    for (int ti = 0; ti < 4; ti++){
      f32x4 v = acc[ti][tj];
      #pragma unroll
      for (int r = 0; r < 4; r++){
        float x   = v[r] + bn;
        float act = (gl == 2) ? tanh_fast(x) : sigf(x);   // lane's own gate only
        float iv = __shfl(act, sbase);
        float fv = __shfl(act, sbase + 1);
        float gv = __shfl(act, sbase + 2);
        float ov = __shfl(act, sbase + 3);
        float cn = fmaf(fv, cp[ti*4 + r], iv*gv);
        float hn = ov * tanh_fast(cn);
        int m = m_w + ti*16 + quad*4 + r;
        if (gl == 0)      cptr[(size_t)m*HID + unit] = cn;
        else if (gl == 1) hout[(size_t)m*HID + unit] = (f16)hn;
      }
    }
  }
}

// ================= final output GEMM =================
__global__ __launch_bounds__(256, 2) void k_final(const char* __restrict__ ws,
                                                  const float* __restrict__ bd,
                                                  float* __restrict__ dout)
{
  __shared__ __align__(16) char ldsA[16384];
  __shared__ __align__(16) char ldsB[16384];
  const int w = threadIdx.x >> 6, lane = threadIdx.x & 63;
  const int n0 = blockIdx.x*128, m0 = blockIdx.y*128;
  const f16* A  = (const f16*)(ws + OFF_H2ALL);
  const f16* Bp = (const f16*)(ws + OFF_WD);

  f32x4 acc[4][4];
  f32x4 zero = {0.f, 0.f, 0.f, 0.f};
  #pragma unroll
  for (int i = 0; i < 4; i++)
    #pragma unroll
    for (int j = 0; j < 4; j++) acc[i][j] = zero;

  gemm_tile(acc, A, m0, HID, Bp, n0, HID, ldsA, ldsB, w, lane);

  const int m_w = (w>>1)*64, n_w = (w&1)*64, quad = lane>>4, c15 = lane&15;
  #pragma unroll
  for (int tj = 0; tj < 4; tj++){
    int o = n0 + n_w + tj*16 + c15;
    bool valid = (o < 227);
    float bn = valid ? bd[o] : 0.f;
    #pragma unroll
    for (int ti = 0; ti < 4; ti++){
      f32x4 v = acc[ti][tj];
      #pragma unroll
      for (int r = 0; r < 4; r++){
        int m = m0 + m_w + ti*16 + quad*4 + r;
        if (valid){
          int tt = m >> 8, b = m & 255;
          dout[(size_t)b*22700 + (size_t)tt*227 + o] = v[r] + bn;
        }
      }
    }
  }
}

// ================= host =================
extern "C" void kernel_launch(void* const* d_in, const int* in_sizes, int n_in,
                              void* d_out, int out_size, void* d_ws, size_t ws_size,
                              hipStream_t stream)
{
  (void)in_sizes; (void)n_in; (void)out_size; (void)ws_size;
  const float* seq  = (const float*)d_in[0];
  const float* Wih1 = (const float*)d_in[1];
  const float* Whh1 = (const float*)d_in[2];
  const float* bih1 = (const float*)d_in[3];
  const float* bhh1 = (const float*)d_in[4];
  const float* Wih2 = (const float*)d_in[5];
  const float* Whh2 = (const float*)d_in[6];
  const float* bih2 = (const float*)d_in[7];
  const float* bhh2 = (const float*)d_in[8];
  const float* Wih3 = (const float*)d_in[9];
  const float* Whh3 = (const float*)d_in[10];
  const float* bih3 = (const float*)d_in[11];
  const float* bhh3 = (const float*)d_in[12];
  const float* Wd   = (const float*)d_in[13];
  const float* bd   = (const float*)d_in[14];
  char* ws = (char*)d_ws;

  hipMemsetAsync(ws + OFF_C,    0, (size_t)3*BB*HID*4, stream);
  hipMemsetAsync(ws + OFF_HBUF, 0, (size_t)2*BB*HID*2, stream);
  hipMemsetAsync(ws + OFF_H2Z,  0, (size_t)BB*HID*2,   stream);

  k_pack5   <<<dim3(2048, 5), dim3(256), 0, stream>>>(Whh1, Wih2, Whh2, Wih3, Whh3, ws);
  k_packwih1<<<dim3(4096),    dim3(256), 0, stream>>>(Wih1, ws);
  k_packwd  <<<dim3(256),     dim3(256), 0, stream>>>(Wd, ws);
  k_packwdt <<<dim3(1024),    dim3(256), 0, stream>>>(Wd, ws);
  k_xpad    <<<dim3(25600),   dim3(256), 0, stream>>>(seq, ws);
  k_bias    <<<dim3(16),      dim3(256), 0, stream>>>(bih1, bhh1, bih2, bhh2, bih3, bhh3, Wih1, bd, ws);
  k_w1d     <<<dim3(8, 32),   dim3(256), 0, stream>>>(ws);

  for (int t = 0; t < TT; t++){
    int ug = ((t % 10) < 5) ? 1 : 0;
    k_step<<<dim3(64, 3), dim3(256), 0, stream>>>(ws, t, ug);
  }

  k_final<<<dim3(2, 200), dim3(256), 0, stream>>>((const char*)ws, bd, (float*)d_out);
}